// Round 2
// baseline (795.841 us; speedup 1.0000x reference)
//
#include <hip/hip_runtime.h>
#include <math.h>

#define KK 9
#define BB 8
#define CC 64
#define OO 64
#define HH 128
#define WW 128
#define HWSZ (HH*WW)

typedef _Float16 half8 __attribute__((ext_vector_type(8)));
typedef float    floatx4 __attribute__((ext_vector_type(4)));

// ws layout (f16): Wp[9][2][4][32][8] | Wd[9][2][4][64][8] | x_h[B][2][HW][32] (planar ch-halves)
#define WP_ELEMS (9*2*4*32*8)   // 18432
#define WD_ELEMS (9*2*4*64*8)   // 36864
#define XH_ELEMS ((size_t)BB*2*HWSZ*32)
#define NCONV 2048

// ---------------- prep: x -> planar channel-half f16 (+ weight repack, frag-ordered) ----------------
__global__ __launch_bounds__(256) void prep(
    const float* __restrict__ x,
    const float* __restrict__ p_w, const float* __restrict__ m_w,
    const float* __restrict__ d_w,
    _Float16* __restrict__ Wp, _Float16* __restrict__ Wd, _Float16* __restrict__ x_h,
    int conv_blocks)
{
    const int blk = blockIdx.x;
    const int tid = threadIdx.x;
    if (blk < conv_blocks) {
        __shared__ _Float16 sh[64][72];
        const int b    = blk >> 8;
        const int pix0 = (blk & 255) * 64;
        const float* xb = x + (size_t)b*CC*HWSZ + pix0;
        {
            const int p     = tid & 63;
            const int cbase = tid >> 6;
            #pragma unroll
            for (int j = 0; j < 16; ++j) {
                const int c = j*4 + cbase;
                sh[p][c] = (_Float16)xb[(size_t)c*HWSZ + p];
            }
        }
        __syncthreads();
        {
            const int p   = tid >> 2;
            const int c0  = (tid & 3) * 16;
            const int ks  = c0 >> 5;          // channel half
            const int loc = c0 & 31;
            _Float16* dst = x_h + (((size_t)(b*2 + ks))*HWSZ + pix0 + p)*32 + loc;
            *(half8*)dst       = *(const half8*)&sh[p][c0];
            *(half8*)(dst + 8) = *(const half8*)&sh[p][c0 + 8];
        }
    } else {
        const int i = (blk - conv_blocks)*256 + tid;
        if (i < WP_ELEMS) {
            // i -> [k][ks][quad][n][e]
            const int e = i & 7, n = (i>>3)&31, quad = (i>>8)&3, ks = (i>>10)&1, k = i>>11;
            const int c = ks*32 + quad*8 + e;
            float v = 0.f;
            if (n < 18)      v = p_w[(n*CC + c)*KK + k];
            else if (n < 27) v = m_w[((n-18)*CC + c)*KK + k];
            Wp[i] = (_Float16)v;
        } else if (i < WP_ELEMS + WD_ELEMS) {
            const int j = i - WP_ELEMS;
            // j -> [k][ks][quad][o][e]
            const int e = j & 7, o = (j>>3)&63, quad = (j>>9)&3, ks = (j>>11)&1, k = j>>12;
            const int c = ks*32 + quad*8 + e;
            Wd[j] = (_Float16)d_w[(o*CC + c)*KK + k];
        }
    }
}

// ---------------- fused DCNv2: LDS-patch gather (kills divergent global requests) ----------------
// grid 2048 (b = blk&7 XCD swizzle, seg -> 64-pixel half-row); block 256 = 4 waves.
// Patch P: phase 1 = [6][72][32] (3 rows x 2 ch-halves), phase 2 = [8][72][32] (rows row-3..row+4,
// one ch-half per pass). 16B chunks XOR-swizzled: slot q^((j>>1)&3) -> ~2-way LDS conflicts (free).
// Out-of-patch samples (|offset|>~3; p < 1e-4) fall back to exec-masked global loads.
__global__ __launch_bounds__(256, 3) void dcn_fused(
    const _Float16* __restrict__ x_h,
    const _Float16* __restrict__ Wp, const _Float16* __restrict__ Wd,
    const float* __restrict__ p_b, const float* __restrict__ m_b,
    const float* __restrict__ db,
    float* __restrict__ out, float* __restrict__ offset_out)
{
    __shared__ alignas(16) _Float16 P[8*72*32];   // 36864 B
    __shared__ alignas(16) float    T[27*68];     // 7344 B

    const int tid  = threadIdx.x;
    const int wv   = tid >> 6;
    const int lane = tid & 63;
    const int quad = lane >> 4;
    const int l15  = lane & 15;
    const int b    = blockIdx.x & 7;
    const int seg  = blockIdx.x >> 3;      // 0..255
    const int row  = seg >> 1;
    const int col0 = (seg & 1) * 64;
    const int pix0 = row * WW + col0;
    const int px   = wv*16 + l15;          // block-local pixel 0..63
    const int wx   = col0 + px;            // global x coordinate
    const _Float16* xb0 = x_h + ((size_t)(b*2 + 0))*HWSZ*32;
    const _Float16* xb1 = x_h + ((size_t)(b*2 + 1))*HWSZ*32;

    // ---- stage phase-1 patch: rows row-1..row+1, both ch-halves -> slots [ri*2+ks][72][32]
    #pragma unroll
    for (int rr = 0; rr < 7; ++rr) {
        const int c = rr*256 + tid;
        if (rr < 6 || c < 1728) {
            const int s = c / 288, rem = c % 288;
            const int j = rem >> 2, q = rem & 3;
            const int rI = s >> 1, ks = s & 1;
            const int sr = min(max(row - 1 + rI, 0), HH-1);
            const int sc = min(max(col0 - 3 + j, 0), WW-1);
            const _Float16* src = (ks ? xb1 : xb0) + ((size_t)(sr*WW + sc))*32 + q*8;
            *(half8*)&P[(s*72 + j)*32 + ((q ^ ((j>>1)&3))<<3)] = *(const half8*)src;
        }
    }
    __syncthreads();

    // =============== phase 1: offset(18)+mask(9) conv — LDS A-frags, global weights, no barriers
    floatx4 accp[2];
    accp[0] = (floatx4)0.f; accp[1] = (floatx4)0.f;
    #pragma unroll
    for (int k = 0; k < 9; ++k) {
        const int ky = k/3, kx = k%3;
        const int hy = row + ky - 1;
        const int hx = wx  + kx - 1;
        const bool vld = (hy >= 0) & (hy < HH) & (hx >= 0) & (hx < WW);
        const int j   = px + kx + 2;
        const int swz = (quad ^ ((j>>1)&3)) << 3;
        half8 a0 = *(const half8*)&P[((2*ky    )*72 + j)*32 + swz];
        half8 a1 = *(const half8*)&P[((2*ky + 1)*72 + j)*32 + swz];
        const half8 z = (half8)(_Float16)0.f;
        a0 = vld ? a0 : z;
        a1 = vld ? a1 : z;
        const _Float16* wp = Wp + k*2048 + quad*256 + l15*8;
        accp[0] = __builtin_amdgcn_mfma_f32_16x16x32_f16(a0, *(const half8*)(wp),              accp[0], 0, 0, 0);
        accp[1] = __builtin_amdgcn_mfma_f32_16x16x32_f16(a0, *(const half8*)(wp + 128),        accp[1], 0, 0, 0);
        accp[0] = __builtin_amdgcn_mfma_f32_16x16x32_f16(a1, *(const half8*)(wp + 1024),       accp[0], 0, 0, 0);
        accp[1] = __builtin_amdgcn_mfma_f32_16x16x32_f16(a1, *(const half8*)(wp + 1024 + 128), accp[1], 0, 0, 0);
    }

    // epilogue 1: D-frags -> T (bias folded), barrier, params to regs + offsets out
    #pragma unroll
    for (int nt = 0; nt < 2; ++nt) {
        const int ch = nt*16 + l15;
        if (ch < 27) {
            const float bias = (ch < 18) ? p_b[ch] : m_b[ch-18];
            #pragma unroll
            for (int r = 0; r < 4; ++r)
                T[ch*68 + wv*16 + quad*4 + r] = accp[nt][r] + bias;
        }
    }
    __syncthreads();

    float dyk[9], dxk[9], mkk[9];
    #pragma unroll
    for (int k = 0; k < 9; ++k) {
        dyk[k] = T[(2*k  )*68 + px];
        dxk[k] = T[(2*k+1)*68 + px];
        mkk[k] = 1.f / (1.f + expf(-T[(18+k)*68 + px]));
    }
    {
        float* offp = offset_out + (size_t)b*18*HWSZ + pix0;
        #pragma unroll
        for (int j = 0; j < 5; ++j) {
            const int idx = j*256 + tid;
            if (idx < 18*64) {
                const int ch = idx >> 6, p2 = idx & 63;
                offp[ch*HWSZ + p2] = T[ch*68 + p2];
            }
        }
    }

    // =============== phase 2: modulated deformable conv — 2 passes over channel halves
    floatx4 acc[4];
    #pragma unroll
    for (int nt = 0; nt < 4; ++nt) acc[nt] = (floatx4)0.f;

    for (int ks = 0; ks < 2; ++ks) {
        const _Float16* xpk = ks ? xb1 : xb0;
        __syncthreads();   // previous patch users done
        // stage patch: rows row-3..row+4, ch-half ks -> [8][72][32]
        #pragma unroll
        for (int rr = 0; rr < 9; ++rr) {
            const int c = rr*256 + tid;   // < 2304 exactly
            const int i = c / 288, rem = c % 288;
            const int j = rem >> 2, q = rem & 3;
            const int sr = min(max(row - 3 + i, 0), HH-1);
            const int sc = min(max(col0 - 3 + j, 0), WW-1);
            const half8 v = *(const half8*)(xpk + ((size_t)(sr*WW + sc))*32 + q*8);
            *(half8*)&P[(i*72 + j)*32 + ((q ^ ((j>>1)&3))<<3)] = v;
        }
        __syncthreads();

        #pragma unroll
        for (int k = 0; k < 9; ++k) {
            const float dy = dyk[k], dx = dxk[k], mk = mkk[k];
            const float py  = (float)(row - 1 + k/3) + dy;
            const float pxf = (float)(wx  - 1 + k%3) + dx;
            const float y0f = floorf(py), x0f = floorf(pxf);
            const int   iy0 = (int)y0f,   ix0 = (int)x0f;
            const float wy1 = py - y0f,   wx1 = pxf - x0f;
            const float wy0 = 1.f - wy1,  wx0 = 1.f - wx1;
            const bool vy0 = ((unsigned)iy0     < (unsigned)HH);
            const bool vy1 = ((unsigned)(iy0+1) < (unsigned)HH);
            const bool vx0 = ((unsigned)ix0     < (unsigned)WW);
            const bool vx1 = ((unsigned)(ix0+1) < (unsigned)WW);
            const int cy0 = min(max(iy0,   0), HH-1), cy1 = min(max(iy0+1, 0), HH-1);
            const int cx0 = min(max(ix0,   0), WW-1), cx1 = min(max(ix0+1, 0), WW-1);
            const _Float16 g0 = (_Float16)(wy0*wx0*((vy0&vx0) ? mk : 0.f));
            const _Float16 g1 = (_Float16)(wy0*wx1*((vy0&vx1) ? mk : 0.f));
            const _Float16 g2 = (_Float16)(wy1*wx0*((vy1&vx0) ? mk : 0.f));
            const _Float16 g3 = (_Float16)(wy1*wx1*((vy1&vx1) ? mk : 0.f));

            const bool inP = (iy0 >= row-3) & (iy0 <= row+3) &
                             (ix0 >= col0-3) & (ix0 <= col0+67);
            half8 c00, c01, c10, c11;
            if (inP) {
                const int i0 = cy0 - row + 3,  i1 = cy1 - row + 3;
                const int j0 = cx0 - col0 + 3, j1 = cx1 - col0 + 3;
                const int s0 = (quad ^ ((j0>>1)&3)) << 3;
                const int s1 = (quad ^ ((j1>>1)&3)) << 3;
                c00 = *(const half8*)&P[(i0*72 + j0)*32 + s0];
                c01 = *(const half8*)&P[(i0*72 + j1)*32 + s1];
                c10 = *(const half8*)&P[(i1*72 + j0)*32 + s0];
                c11 = *(const half8*)&P[(i1*72 + j1)*32 + s1];
            } else {
                c00 = *(const half8*)(xpk + ((size_t)(cy0*WW + cx0))*32 + quad*8);
                c01 = *(const half8*)(xpk + ((size_t)(cy0*WW + cx1))*32 + quad*8);
                c10 = *(const half8*)(xpk + ((size_t)(cy1*WW + cx0))*32 + quad*8);
                c11 = *(const half8*)(xpk + ((size_t)(cy1*WW + cx1))*32 + quad*8);
            }
            const half8 af = c00*g0 + c01*g1 + c10*g2 + c11*g3;

            const _Float16* wdp = Wd + k*4096 + ks*2048 + quad*512 + l15*8;
            #pragma unroll
            for (int nt = 0; nt < 4; ++nt)
                acc[nt] = __builtin_amdgcn_mfma_f32_16x16x32_f16(af, *(const half8*)(wdp + nt*128), acc[nt], 0, 0, 0);
        }
    }

    // epilogue 2: 4 chunks of 16 output channels via LDS transpose (aliases P)
    __syncthreads();
    float* T2 = (float*)&P[0];   // [16][68]
    #pragma unroll
    for (int oc = 0; oc < 4; ++oc) {
        #pragma unroll
        for (int r = 0; r < 4; ++r)
            T2[l15*68 + wv*16 + quad*4 + r] = acc[oc][r];
        __syncthreads();
        #pragma unroll
        for (int j = 0; j < 4; ++j) {
            const int idx = j*256 + tid;
            const int o16 = idx >> 6, p2 = idx & 63;
            out[((size_t)b*OO + oc*16 + o16)*HWSZ + pix0 + p2] = T2[o16*68 + p2] + db[oc*16 + o16];
        }
        __syncthreads();
    }
}

// ---------------- fallback (ws too small): R5-style LDS kernel, fp32 gather ----------------
__global__ __launch_bounds__(256, 4) void dcn_fused_lds(
    const float* __restrict__ x,
    const _Float16* __restrict__ Wp, const _Float16* __restrict__ Wd,
    const float* __restrict__ p_b, const float* __restrict__ m_b,
    const float* __restrict__ db,
    float* __restrict__ out, float* __restrict__ offset_out)
{
    __shared__ alignas(16) _Float16 A_sh[128][72];
    __shared__ alignas(16) _Float16 WM_sh[32*72];
    __shared__ alignas(16) _Float16 Wd_sh[64][72];

    const int tid   = threadIdx.x;
    const int wv    = tid >> 6;
    const int lane  = tid & 63;
    const int quad  = lane >> 4;
    const int l15   = lane & 15;
    const int b     = blockIdx.x & 7;
    const int row   = blockIdx.x >> 3;
    const int pix0  = row * WW;
    const int p     = tid & 127;
    const int chalf = (tid >> 7) * 32;
    const int h = row, w = p;
    const float* xb = x + (size_t)b*CC*HWSZ;
    _Float16 (*W_sh)[72] = (_Float16 (*)[72])WM_sh;

    floatx4 accp[2][2];
    #pragma unroll
    for (int mt = 0; mt < 2; ++mt)
        #pragma unroll
        for (int nt = 0; nt < 2; ++nt) accp[mt][nt] = (floatx4)0.f;

    for (int k = 0; k < 9; ++k) {
        {
            const int n  = tid >> 3;
            const int c0 = (tid & 7) * 8;
            *(half8*)&W_sh[n][c0] =
                *(const half8*)(Wp + k*2048 + (c0>>5)*1024 + ((c0>>3)&3)*256 + n*8);
        }
        const int hy = h + (k/3) - 1;
        const int wx = w + (k%3) - 1;
        const bool vld = (hy >= 0) & (hy < HH) & (wx >= 0) & (wx < WW);
        const float* xs = xb + hy*WW + wx;
        #pragma unroll
        for (int cb = 0; cb < 4; ++cb) {
            union { half8 v; _Float16 e[8]; } u;
            #pragma unroll
            for (int j = 0; j < 8; ++j)
                u.e[j] = (_Float16)(vld ? xs[(size_t)(chalf + cb*8 + j)*HWSZ] : 0.f);
            *(half8*)&A_sh[p][chalf + cb*8] = u.v;
        }
        __syncthreads();
        #pragma unroll
        for (int ks = 0; ks < 2; ++ks) {
            half8 bf[2];
            #pragma unroll
            for (int nt = 0; nt < 2; ++nt)
                bf[nt] = *(const half8*)&W_sh[nt*16 + l15][ks*32 + quad*8];
            #pragma unroll
            for (int mt = 0; mt < 2; ++mt) {
                half8 af = *(const half8*)&A_sh[wv*32 + mt*16 + l15][ks*32 + quad*8];
                accp[mt][0] = __builtin_amdgcn_mfma_f32_16x16x32_f16(af, bf[0], accp[mt][0], 0, 0, 0);
                accp[mt][1] = __builtin_amdgcn_mfma_f32_16x16x32_f16(af, bf[1], accp[mt][1], 0, 0, 0);
            }
        }
        __syncthreads();
    }

    float (*T)[132] = (float (*)[132])&A_sh[0][0];
    #pragma unroll
    for (int nt = 0; nt < 2; ++nt) {
        const int ch = nt*16 + l15;
        if (ch < 27) {
            #pragma unroll
            for (int mt = 0; mt < 2; ++mt)
                #pragma unroll
                for (int r = 0; r < 4; ++r)
                    T[ch][wv*32 + mt*16 + quad*4 + r] = accp[mt][nt][r];
        }
    }
    __syncthreads();

    float dyk[9], dxk[9], mkk[9];
    float* offp = offset_out + (size_t)b*18*HWSZ + pix0;
    #pragma unroll
    for (int k = 0; k < 9; ++k) {
        dyk[k] = T[2*k][p]   + p_b[2*k];
        dxk[k] = T[2*k+1][p] + p_b[2*k+1];
        mkk[k] = 1.f / (1.f + expf(-(T[18+k][p] + m_b[k])));
    }
    if (tid < 128) {
        #pragma unroll
        for (int k = 0; k < 9; ++k) {
            offp[(2*k  )*HWSZ + p] = dyk[k];
            offp[(2*k+1)*HWSZ + p] = dxk[k];
        }
    }
    __syncthreads();

    floatx4 acc[2][4];
    #pragma unroll
    for (int mt = 0; mt < 2; ++mt)
        #pragma unroll
        for (int nt = 0; nt < 4; ++nt) acc[mt][nt] = (floatx4)0.f;

    for (int k = 0; k < 9; ++k) {
        {
            const int o  = tid >> 2;
            const int c0 = (tid & 3) * 16;
            *(half8*)&Wd_sh[o][c0] =
                *(const half8*)(Wd + k*4096 + (c0>>5)*2048 + ((c0>>3)&3)*512 + o*8);
            const int c8 = c0 + 8;
            *(half8*)&Wd_sh[o][c8] =
                *(const half8*)(Wd + k*4096 + (c8>>5)*2048 + ((c8>>3)&3)*512 + o*8);
        }
        const float mk = mkk[k];
        const float py = (float)(h - 1 + k/3) + dyk[k];
        const float px = (float)(w - 1 + k%3) + dxk[k];
        const float y0f = floorf(py), x0f = floorf(px);
        const int   iy0 = (int)y0f,   ix0 = (int)x0f;
        const float wy1 = py - y0f,   wx1 = px - x0f;
        const float wy0 = 1.f - wy1,  wx0 = 1.f - wx1;
        const bool vy0 = (iy0   >= 0) & (iy0   < HH);
        const bool vy1 = (iy0+1 >= 0) & (iy0+1 < HH);
        const bool vx0 = (ix0   >= 0) & (ix0   < WW);
        const bool vx1 = (ix0+1 >= 0) & (ix0+1 < WW);
        const int cy0 = min(max(iy0,   0), HH-1), cy1 = min(max(iy0+1, 0), HH-1);
        const int cx0 = min(max(ix0,   0), WW-1), cx1 = min(max(ix0+1, 0), WW-1);
        const int i0 = cy0*WW+cx0; const float w0 = wy0*wx0*((vy0&vx0) ? mk : 0.f);
        const int i1 = cy0*WW+cx1; const float w1 = wy0*wx1*((vy0&vx1) ? mk : 0.f);
        const int i2 = cy1*WW+cx0; const float w2 = wy1*wx0*((vy1&vx0) ? mk : 0.f);
        const int i3 = cy1*WW+cx1; const float w3 = wy1*wx1*((vy1&vx1) ? mk : 0.f);
        #pragma unroll
        for (int cb = 0; cb < 4; ++cb) {
            union { half8 v; _Float16 e[8]; } u;
            #pragma unroll
            for (int j = 0; j < 8; ++j) {
                const float* xc = xb + (size_t)(chalf + cb*8 + j)*HWSZ;
                u.e[j] = (_Float16)(w0*xc[i0] + w1*xc[i1] + w2*xc[i2] + w3*xc[i3]);
            }
            *(half8*)&A_sh[p][chalf + cb*8] = u.v;
        }
        __syncthreads();
        #pragma unroll
        for (int ks = 0; ks < 2; ++ks) {
            half8 bf[4];
            #pragma unroll
            for (int nt = 0; nt < 4; ++nt)
                bf[nt] = *(const half8*)&Wd_sh[nt*16 + l15][ks*32 + quad*8];
            #pragma unroll
            for (int mt = 0; mt < 2; ++mt) {
                half8 af = *(const half8*)&A_sh[wv*32 + mt*16 + l15][ks*32 + quad*8];
                #pragma unroll
                for (int nt = 0; nt < 4; ++nt)
                    acc[mt][nt] = __builtin_amdgcn_mfma_f32_16x16x32_f16(af, bf[nt], acc[mt][nt], 0, 0, 0);
            }
        }
        __syncthreads();
    }

    float (*T2)[132] = (float (*)[132])&A_sh[0][0];
    #pragma unroll
    for (int oc = 0; oc < 4; ++oc) {
        #pragma unroll
        for (int mt = 0; mt < 2; ++mt)
            #pragma unroll
            for (int r = 0; r < 4; ++r)
                T2[l15][wv*32 + mt*16 + quad*4 + r] = acc[mt][oc][r];
        __syncthreads();
        #pragma unroll
        for (int j = 0; j < 8; ++j) {
            const int idx = tid + j*256;
            const int o16 = idx >> 7, p2 = idx & 127;
            out[((size_t)b*OO + oc*16 + o16)*HWSZ + pix0 + p2] = T2[o16][p2] + db[oc*16 + o16];
        }
        __syncthreads();
    }
}

extern "C" void kernel_launch(void* const* d_in, const int* in_sizes, int n_in,
                              void* d_out, int out_size, void* d_ws, size_t ws_size,
                              hipStream_t stream) {
    const float* x   = (const float*)d_in[0];
    const float* p_w = (const float*)d_in[1];
    const float* p_b = (const float*)d_in[2];
    const float* m_w = (const float*)d_in[3];
    const float* m_b = (const float*)d_in[4];
    const float* dw  = (const float*)d_in[5];
    const float* db  = (const float*)d_in[6];

    float* out        = (float*)d_out;             // (B,O,H,W)
    float* offset_out = out + (size_t)BB*OO*HWSZ;  // (B,18,H,W)

    _Float16* Wp  = (_Float16*)d_ws;
    _Float16* Wd  = Wp + WP_ELEMS;
    _Float16* x_h = Wd + WD_ELEMS;

    const int nrep = (WP_ELEMS + WD_ELEMS + 255) / 256;
    const size_t need = (size_t)(WP_ELEMS + WD_ELEMS + XH_ELEMS) * sizeof(_Float16);
    if (ws_size >= need) {
        prep<<<dim3(NCONV + nrep), 256, 0, stream>>>(x, p_w, m_w, dw, Wp, Wd, x_h, NCONV);
        dcn_fused<<<dim3(256*BB), 256, 0, stream>>>(x_h, Wp, Wd, p_b, m_b, db, out, offset_out);
    } else {
        prep<<<dim3(nrep), 256, 0, stream>>>(x, p_w, m_w, dw, Wp, Wd, x_h, 0);
        dcn_fused_lds<<<dim3(128*BB), 256, 0, stream>>>(x, Wp, Wd, p_b, m_b, db, out, offset_out);
    }
}

// Round 3
// 149.986 us; speedup vs baseline: 5.3061x; 5.3061x over previous
//
#include <hip/hip_runtime.h>
#include <math.h>

#define KK 9
#define BB 8
#define CC 64
#define OO 64
#define HH 128
#define WW 128
#define HWSZ (HH*WW)

typedef _Float16 half8 __attribute__((ext_vector_type(8)));
typedef float    floatx4 __attribute__((ext_vector_type(4)));

// ws layout (f16): Wp[9][2][4][32][8] | Wd[9][2][4][64][8] | x_h[B][HW][64]
// Frag order: element (k, ks, quad, n, e) holds W[n][c] with c = ks*32 + quad*8 + e
#define WP_ELEMS (9*2*4*32*8)   // 18432
#define WD_ELEMS (9*2*4*64*8)   // 36864
#define XH_ELEMS ((size_t)BB*HWSZ*64)
#define NCONV 2048

// ---------------- prep: x -> channel-last f16 (+ weight repack, frag-ordered) ----------------
__global__ __launch_bounds__(256) void prep(
    const float* __restrict__ x,
    const float* __restrict__ p_w, const float* __restrict__ m_w,
    const float* __restrict__ d_w,
    _Float16* __restrict__ Wp, _Float16* __restrict__ Wd, _Float16* __restrict__ x_h,
    int conv_blocks)
{
    const int blk = blockIdx.x;
    const int tid = threadIdx.x;
    if (blk < conv_blocks) {
        __shared__ _Float16 sh[64][72];
        const int b    = blk >> 8;
        const int pix0 = (blk & 255) * 64;
        const float* xb = x + (size_t)b*CC*HWSZ + pix0;
        {
            const int p     = tid & 63;
            const int cbase = tid >> 6;
            #pragma unroll
            for (int j = 0; j < 16; ++j) {
                const int c = j*4 + cbase;
                sh[p][c] = (_Float16)xb[(size_t)c*HWSZ + p];
            }
        }
        __syncthreads();
        {
            const int p  = tid >> 2;
            const int c0 = (tid & 3) * 16;
            _Float16* dst = x_h + ((size_t)b*HWSZ + pix0 + p)*64 + c0;
            *(half8*)dst       = *(const half8*)&sh[p][c0];
            *(half8*)(dst + 8) = *(const half8*)&sh[p][c0 + 8];
        }
    } else {
        const int i = (blk - conv_blocks)*256 + tid;
        if (i < WP_ELEMS) {
            // i -> [k][ks][quad][n][e]
            const int e = i & 7, n = (i>>3)&31, quad = (i>>8)&3, ks = (i>>10)&1, k = i>>11;
            const int c = ks*32 + quad*8 + e;
            float v = 0.f;
            if (n < 18)      v = p_w[(n*CC + c)*KK + k];
            else if (n < 27) v = m_w[((n-18)*CC + c)*KK + k];
            Wp[i] = (_Float16)v;
        } else if (i < WP_ELEMS + WD_ELEMS) {
            const int j = i - WP_ELEMS;
            // j -> [k][ks][quad][o][e]
            const int e = j & 7, o = (j>>3)&63, quad = (j>>9)&3, ks = (j>>11)&1, k = j>>12;
            const int c = ks*32 + quad*8 + e;
            Wd[j] = (_Float16)d_w[(o*CC + c)*KK + k];
        }
    }
}

// ---------------- fused DCNv2: pixel-major coalesced gather + ds_bpermute to MFMA order ----
// grid 2048 (b = blk&7 XCD swizzle, seg -> 64-pixel half-row); block 256 = 4 waves.
// Phase-2 gather lane map: lane l gathers pixel (l>>2), 16B part (l&3) -> every consecutive
// 4-lane group reads ONE contiguous 64B line (TA-coalesced). 8 ds_bpermute/tap restore the
// MFMA A-fragment order in-register (bijective, no barriers, bit-identical numerics).
__global__ __launch_bounds__(256, 3) void dcn_fused(
    const _Float16* __restrict__ x_h,
    const _Float16* __restrict__ Wp, const _Float16* __restrict__ Wd,
    const float* __restrict__ p_b, const float* __restrict__ m_b,
    const float* __restrict__ db,
    float* __restrict__ out, float* __restrict__ offset_out)
{
    __shared__ alignas(16) float    T[27*68];        // conv1 out (bias folded), 7344 B
    __shared__ alignas(16) _Float16 WS[2][4096];     // phase-2 weight dbuf, 16384 B; T2 aliases

    const int tid  = threadIdx.x;
    const int wv   = tid >> 6;
    const int lane = tid & 63;
    const int quad = lane >> 4;
    const int l15  = lane & 15;
    const int b    = blockIdx.x & 7;
    const int seg  = blockIdx.x >> 3;      // 0..255
    const int row  = seg >> 1;
    const int col0 = (seg & 1) * 64;
    const int pix0 = row * WW + col0;
    const int px   = wv*16 + l15;          // MFMA-order pixel 0..63
    const int wx   = col0 + px;            // global x coordinate (phase 1)
    const _Float16* xbh = x_h + (size_t)b*HWSZ*64;

    // prologue: issue phase-2 tap-0 weight stage loads early
    half8 ws0a = *(const half8*)(Wd + tid*16);
    half8 ws0b = *(const half8*)(Wd + tid*16 + 8);

    // =============== phase 1: offset(18)+mask(9) conv — no LDS, no barriers ===============
    floatx4 accp[2];
    accp[0] = (floatx4)0.f; accp[1] = (floatx4)0.f;
    #pragma unroll
    for (int k = 0; k < 9; ++k) {
        const int hy = row + k/3 - 1;
        const int hx = wx  + k%3 - 1;
        const bool vld = (hy >= 0) & (hy < HH) & (hx >= 0) & (hx < WW);
        const _Float16* ap = xbh + (size_t)(vld ? hy*WW + hx : 0)*64 + quad*8;
        const half8 z = (half8)(_Float16)0.f;
        half8 a0 = *(const half8*)ap;
        half8 a1 = *(const half8*)(ap + 32);
        a0 = vld ? a0 : z;
        a1 = vld ? a1 : z;
        const _Float16* wp = Wp + k*2048 + quad*256 + l15*8;
        #pragma unroll
        for (int ks = 0; ks < 2; ++ks) {
            const half8 af = ks ? a1 : a0;
            accp[0] = __builtin_amdgcn_mfma_f32_16x16x32_f16(af, *(const half8*)(wp + ks*1024),       accp[0], 0, 0, 0);
            accp[1] = __builtin_amdgcn_mfma_f32_16x16x32_f16(af, *(const half8*)(wp + ks*1024 + 128), accp[1], 0, 0, 0);
        }
    }

    // epilogue 1: D-frags -> T (bias folded), stage tap-0 weights, one barrier
    #pragma unroll
    for (int nt = 0; nt < 2; ++nt) {
        const int ch = nt*16 + l15;
        if (ch < 27) {
            const float bias = (ch < 18) ? p_b[ch] : m_b[ch-18];
            #pragma unroll
            for (int r = 0; r < 4; ++r)
                T[ch*68 + wv*16 + quad*4 + r] = accp[nt][r] + bias;
        }
    }
    {
        _Float16* wd = &WS[0][tid*16];
        *(half8*)wd     = ws0a;
        *(half8*)(wd+8) = ws0b;
    }
    __syncthreads();

    // offsets -> global (T rows 0..17 already biased)
    {
        float* offp = offset_out + (size_t)b*18*HWSZ + pix0;
        #pragma unroll
        for (int j = 0; j < 5; ++j) {
            const int idx = j*256 + tid;
            if (idx < 18*64) {
                const int ch = idx >> 6, p2i = idx & 63;
                offp[ch*HWSZ + p2i] = T[ch*68 + p2i];
            }
        }
    }

    // =============== phase 2: modulated deformable conv — 1 barrier per tap ===============
    // gather-order identity for this lane:
    const int p2   = wv*16 + (lane >> 2);   // pixel this lane gathers/combines
    const int part = lane & 3;              // 16B part within the pixel's 128B record
    const int wx2  = col0 + p2;
    // bpermute byte-index: MFMA lane m pulls from gather lane ((m&15)<<2)|(m>>4)
    const int bidx = ((l15 << 2) | quad) << 2;

    float dyk[9], dxk[9], mkk[9];
    #pragma unroll
    for (int k = 0; k < 9; ++k) {
        dyk[k] = T[(2*k  )*68 + p2];
        dxk[k] = T[(2*k+1)*68 + p2];
        mkk[k] = 1.f / (1.f + expf(-T[(18+k)*68 + p2]));
    }

    floatx4 acc[4];
    #pragma unroll
    for (int nt = 0; nt < 4; ++nt) acc[nt] = (floatx4)0.f;

    #pragma unroll
    for (int k = 0; k < 9; ++k) {
        // stage loads for tap k+1 (fly across the barrier; consumed at end of body)
        half8 wsa, wsb;
        if (k < 8) {
            const _Float16* wsrc = Wd + (k+1)*4096 + tid*16;
            wsa = *(const half8*)wsrc;
            wsb = *(const half8*)(wsrc + 8);
        }

        const float dy = dyk[k], dx = dxk[k], mk = mkk[k];
        const float py  = (float)(row - 1 + k/3) + dy;
        const float pxf = (float)(wx2 - 1 + k%3) + dx;
        const float y0f = floorf(py), x0f = floorf(pxf);
        const int   iy0 = (int)y0f,   ix0 = (int)x0f;
        const float wy1 = py - y0f,   wx1 = pxf - x0f;
        const float wy0 = 1.f - wy1,  wx0 = 1.f - wx1;
        const bool vy0 = ((unsigned)iy0     < (unsigned)HH);
        const bool vy1 = ((unsigned)(iy0+1) < (unsigned)HH);
        const bool vx0 = ((unsigned)ix0     < (unsigned)WW);
        const bool vx1 = ((unsigned)(ix0+1) < (unsigned)WW);
        const int cy0 = min(max(iy0,   0), HH-1), cy1 = min(max(iy0+1, 0), HH-1);
        const int cx0 = min(max(ix0,   0), WW-1), cx1 = min(max(ix0+1, 0), WW-1);
        const int i0 = cy0*WW+cx0, i1 = cy0*WW+cx1, i2 = cy1*WW+cx0, i3 = cy1*WW+cx1;
        const _Float16 g0 = (_Float16)(wy0*wx0*((vy0&vx0) ? mk : 0.f));
        const _Float16 g1 = (_Float16)(wy0*wx1*((vy0&vx1) ? mk : 0.f));
        const _Float16 g2 = (_Float16)(wy1*wx0*((vy1&vx0) ? mk : 0.f));
        const _Float16 g3 = (_Float16)(wy1*wx1*((vy1&vx1) ? mk : 0.f));

        // pixel-major coalesced gather: 4-lane group = one 64B line per load
        const _Float16* c0p = xbh + (size_t)i0*64 + part*8;
        const _Float16* c1p = xbh + (size_t)i1*64 + part*8;
        const _Float16* c2p = xbh + (size_t)i2*64 + part*8;
        const _Float16* c3p = xbh + (size_t)i3*64 + part*8;
        const half8 p0l = *(const half8*)c0p, p0h = *(const half8*)(c0p + 32);
        const half8 p1l = *(const half8*)c1p, p1h = *(const half8*)(c1p + 32);
        const half8 p2l = *(const half8*)c2p, p2h = *(const half8*)(c2p + 32);
        const half8 p3l = *(const half8*)c3p, p3h = *(const half8*)(c3p + 32);
        const half8 lo = p0l*g0 + p1l*g1 + p2l*g2 + p3l*g3;   // ch [part*8, +8)   of p2
        const half8 hi = p0h*g0 + p1h*g1 + p2h*g2 + p3h*g3;   // ch [32+part*8,+8) of p2

        // in-register transpose to MFMA A-fragment order (bijective bpermute)
        union U { half8 h; int i[4]; };
        U ulo, uhi, a0u, a1u;
        ulo.h = lo; uhi.h = hi;
        #pragma unroll
        for (int d = 0; d < 4; ++d) {
            a0u.i[d] = __builtin_amdgcn_ds_bpermute(bidx, ulo.i[d]);
            a1u.i[d] = __builtin_amdgcn_ds_bpermute(bidx, uhi.i[d]);
        }

        // MFMA from current weight buffer (linear frag-order reads, phase-conflict-free)
        #pragma unroll
        for (int ks = 0; ks < 2; ++ks) {
            const half8 af = ks ? a1u.h : a0u.h;
            const _Float16* wsp = &WS[k&1][ks*2048 + quad*512 + l15*8];
            #pragma unroll
            for (int nt = 0; nt < 4; ++nt)
                acc[nt] = __builtin_amdgcn_mfma_f32_16x16x32_f16(af, *(const half8*)(wsp + nt*128), acc[nt], 0, 0, 0);
        }

        // write next tap's weights into the other buffer, single barrier
        if (k < 8) {
            _Float16* wd = &WS[(k+1)&1][tid*16];
            *(half8*)wd     = wsa;
            *(half8*)(wd+8) = wsb;
        }
        __syncthreads();
    }

    // epilogue 2: 4 chunks of 16 output channels via LDS transpose (aliases WS)
    float* T2 = (float*)&WS[0][0];   // [16][68]
    #pragma unroll
    for (int oc = 0; oc < 4; ++oc) {
        #pragma unroll
        for (int r = 0; r < 4; ++r)
            T2[l15*68 + wv*16 + quad*4 + r] = acc[oc][r];
        __syncthreads();
        #pragma unroll
        for (int j = 0; j < 4; ++j) {
            const int idx = j*256 + tid;
            const int o16 = idx >> 6, pp = idx & 63;
            out[((size_t)b*OO + oc*16 + o16)*HWSZ + pix0 + pp] = T2[o16*68 + pp] + db[oc*16 + o16];
        }
        __syncthreads();
    }
}

// ---------------- fallback (ws too small): R5-style LDS kernel, fp32 gather ----------------
__global__ __launch_bounds__(256, 4) void dcn_fused_lds(
    const float* __restrict__ x,
    const _Float16* __restrict__ Wp, const _Float16* __restrict__ Wd,
    const float* __restrict__ p_b, const float* __restrict__ m_b,
    const float* __restrict__ db,
    float* __restrict__ out, float* __restrict__ offset_out)
{
    __shared__ alignas(16) _Float16 A_sh[128][72];
    __shared__ alignas(16) _Float16 WM_sh[32*72];
    __shared__ alignas(16) _Float16 Wd_sh[64][72];

    const int tid   = threadIdx.x;
    const int wv    = tid >> 6;
    const int lane  = tid & 63;
    const int quad  = lane >> 4;
    const int l15   = lane & 15;
    const int b     = blockIdx.x & 7;
    const int row   = blockIdx.x >> 3;
    const int pix0  = row * WW;
    const int p     = tid & 127;
    const int chalf = (tid >> 7) * 32;
    const int h = row, w = p;
    const float* xb = x + (size_t)b*CC*HWSZ;
    _Float16 (*W_sh)[72] = (_Float16 (*)[72])WM_sh;

    floatx4 accp[2][2];
    #pragma unroll
    for (int mt = 0; mt < 2; ++mt)
        #pragma unroll
        for (int nt = 0; nt < 2; ++nt) accp[mt][nt] = (floatx4)0.f;

    for (int k = 0; k < 9; ++k) {
        {
            const int n  = tid >> 3;
            const int c0 = (tid & 7) * 8;
            *(half8*)&W_sh[n][c0] =
                *(const half8*)(Wp + k*2048 + (c0>>5)*1024 + ((c0>>3)&3)*256 + n*8);
        }
        const int hy = h + (k/3) - 1;
        const int wx = w + (k%3) - 1;
        const bool vld = (hy >= 0) & (hy < HH) & (wx >= 0) & (wx < WW);
        const float* xs = xb + hy*WW + wx;
        #pragma unroll
        for (int cb = 0; cb < 4; ++cb) {
            union { half8 v; _Float16 e[8]; } u;
            #pragma unroll
            for (int j = 0; j < 8; ++j)
                u.e[j] = (_Float16)(vld ? xs[(size_t)(chalf + cb*8 + j)*HWSZ] : 0.f);
            *(half8*)&A_sh[p][chalf + cb*8] = u.v;
        }
        __syncthreads();
        #pragma unroll
        for (int ks = 0; ks < 2; ++ks) {
            half8 bf[2];
            #pragma unroll
            for (int nt = 0; nt < 2; ++nt)
                bf[nt] = *(const half8*)&W_sh[nt*16 + l15][ks*32 + quad*8];
            #pragma unroll
            for (int mt = 0; mt < 2; ++mt) {
                half8 af = *(const half8*)&A_sh[wv*32 + mt*16 + l15][ks*32 + quad*8];
                accp[mt][0] = __builtin_amdgcn_mfma_f32_16x16x32_f16(af, bf[0], accp[mt][0], 0, 0, 0);
                accp[mt][1] = __builtin_amdgcn_mfma_f32_16x16x32_f16(af, bf[1], accp[mt][1], 0, 0, 0);
            }
        }
        __syncthreads();
    }

    float (*T)[132] = (float (*)[132])&A_sh[0][0];
    #pragma unroll
    for (int nt = 0; nt < 2; ++nt) {
        const int ch = nt*16 + l15;
        if (ch < 27) {
            #pragma unroll
            for (int mt = 0; mt < 2; ++mt)
                #pragma unroll
                for (int r = 0; r < 4; ++r)
                    T[ch][wv*32 + mt*16 + quad*4 + r] = accp[mt][nt][r];
        }
    }
    __syncthreads();

    float dyk[9], dxk[9], mkk[9];
    float* offp = offset_out + (size_t)b*18*HWSZ + pix0;
    #pragma unroll
    for (int k = 0; k < 9; ++k) {
        dyk[k] = T[2*k][p]   + p_b[2*k];
        dxk[k] = T[2*k+1][p] + p_b[2*k+1];
        mkk[k] = 1.f / (1.f + expf(-(T[18+k][p] + m_b[k])));
    }
    if (tid < 128) {
        #pragma unroll
        for (int k = 0; k < 9; ++k) {
            offp[(2*k  )*HWSZ + p] = dyk[k];
            offp[(2*k+1)*HWSZ + p] = dxk[k];
        }
    }
    __syncthreads();

    floatx4 acc[2][4];
    #pragma unroll
    for (int mt = 0; mt < 2; ++mt)
        #pragma unroll
        for (int nt = 0; nt < 4; ++nt) acc[mt][nt] = (floatx4)0.f;

    for (int k = 0; k < 9; ++k) {
        {
            const int o  = tid >> 2;
            const int c0 = (tid & 3) * 16;
            *(half8*)&Wd_sh[o][c0] =
                *(const half8*)(Wd + k*4096 + (c0>>5)*2048 + ((c0>>3)&3)*512 + o*8);
            const int c8 = c0 + 8;
            *(half8*)&Wd_sh[o][c8] =
                *(const half8*)(Wd + k*4096 + (c8>>5)*2048 + ((c8>>3)&3)*512 + o*8);
        }
        const float mk = mkk[k];
        const float py = (float)(h - 1 + k/3) + dyk[k];
        const float px = (float)(w - 1 + k%3) + dxk[k];
        const float y0f = floorf(py), x0f = floorf(px);
        const int   iy0 = (int)y0f,   ix0 = (int)x0f;
        const float wy1 = py - y0f,   wx1 = px - x0f;
        const float wy0 = 1.f - wy1,  wx0 = 1.f - wx1;
        const bool vy0 = (iy0   >= 0) & (iy0   < HH);
        const bool vy1 = (iy0+1 >= 0) & (iy0+1 < HH);
        const bool vx0 = (ix0   >= 0) & (ix0   < WW);
        const bool vx1 = (ix0+1 >= 0) & (ix0+1 < WW);
        const int cy0 = min(max(iy0,   0), HH-1), cy1 = min(max(iy0+1, 0), HH-1);
        const int cx0 = min(max(ix0,   0), WW-1), cx1 = min(max(ix0+1, 0), WW-1);
        const int i0 = cy0*WW+cx0; const float w0 = wy0*wx0*((vy0&vx0) ? mk : 0.f);
        const int i1 = cy0*WW+cx1; const float w1 = wy0*wx1*((vy0&vx1) ? mk : 0.f);
        const int i2 = cy1*WW+cx0; const float w2 = wy1*wx0*((vy1&vx0) ? mk : 0.f);
        const int i3 = cy1*WW+cx1; const float w3 = wy1*wx1*((vy1&vx1) ? mk : 0.f);
        #pragma unroll
        for (int cb = 0; cb < 4; ++cb) {
            union { half8 v; _Float16 e[8]; } u;
            #pragma unroll
            for (int j = 0; j < 8; ++j) {
                const float* xc = xb + (size_t)(chalf + cb*8 + j)*HWSZ;
                u.e[j] = (_Float16)(w0*xc[i0] + w1*xc[i1] + w2*xc[i2] + w3*xc[i3]);
            }
            *(half8*)&A_sh[p][chalf + cb*8] = u.v;
        }
        __syncthreads();
        #pragma unroll
        for (int ks = 0; ks < 2; ++ks) {
            half8 bf[4];
            #pragma unroll
            for (int nt = 0; nt < 4; ++nt)
                bf[nt] = *(const half8*)&Wd_sh[nt*16 + l15][ks*32 + quad*8];
            #pragma unroll
            for (int mt = 0; mt < 2; ++mt) {
                half8 af = *(const half8*)&A_sh[wv*32 + mt*16 + l15][ks*32 + quad*8];
                #pragma unroll
                for (int nt = 0; nt < 4; ++nt)
                    acc[mt][nt] = __builtin_amdgcn_mfma_f32_16x16x32_f16(af, bf[nt], acc[mt][nt], 0, 0, 0);
            }
        }
        __syncthreads();
    }

    float (*T2)[132] = (float (*)[132])&A_sh[0][0];
    #pragma unroll
    for (int oc = 0; oc < 4; ++oc) {
        #pragma unroll
        for (int mt = 0; mt < 2; ++mt)
            #pragma unroll
            for (int r = 0; r < 4; ++r)
                T2[l15][wv*32 + mt*16 + quad*4 + r] = acc[mt][oc][r];
        __syncthreads();
        #pragma unroll
        for (int j = 0; j < 8; ++j) {
            const int idx = tid + j*256;
            const int o16 = idx >> 7, pp = idx & 127;
            out[((size_t)b*OO + oc*16 + o16)*HWSZ + pix0 + pp] = T2[o16][pp] + db[oc*16 + o16];
        }
        __syncthreads();
    }
}

extern "C" void kernel_launch(void* const* d_in, const int* in_sizes, int n_in,
                              void* d_out, int out_size, void* d_ws, size_t ws_size,
                              hipStream_t stream) {
    const float* x   = (const float*)d_in[0];
    const float* p_w = (const float*)d_in[1];
    const float* p_b = (const float*)d_in[2];
    const float* m_w = (const float*)d_in[3];
    const float* m_b = (const float*)d_in[4];
    const float* dw  = (const float*)d_in[5];
    const float* db  = (const float*)d_in[6];

    float* out        = (float*)d_out;             // (B,O,H,W)
    float* offset_out = out + (size_t)BB*OO*HWSZ;  // (B,18,H,W)

    _Float16* Wp  = (_Float16*)d_ws;
    _Float16* Wd  = Wp + WP_ELEMS;
    _Float16* x_h = Wd + WD_ELEMS;

    const int nrep = (WP_ELEMS + WD_ELEMS + 255) / 256;
    const size_t need = (size_t)(WP_ELEMS + WD_ELEMS + XH_ELEMS) * sizeof(_Float16);
    if (ws_size >= need) {
        prep<<<dim3(NCONV + nrep), 256, 0, stream>>>(x, p_w, m_w, dw, Wp, Wd, x_h, NCONV);
        dcn_fused<<<dim3(256*BB), 256, 0, stream>>>(x_h, Wp, Wd, p_b, m_b, db, out, offset_out);
    } else {
        prep<<<dim3(nrep), 256, 0, stream>>>(x, p_w, m_w, dw, Wp, Wd, x_h, 0);
        dcn_fused_lds<<<dim3(128*BB), 256, 0, stream>>>(x, Wp, Wd, p_b, m_b, db, out, offset_out);
    }
}